// Round 9
// baseline (1874.168 us; speedup 1.0000x reference)
//
#include <hip/hip_runtime.h>
#include <hip/hip_bf16.h>
#include <hip/hip_fp16.h>

#define NN 262144
#define EE 4194304
#define NG 16
#define NPER 16384
#define KK 7
#define TPAD 20

__device__ __forceinline__ float wred(float v) {
    #pragma unroll
    for (int o = 32; o > 0; o >>= 1) v += __shfl_xor(v, o);
    return v;
}

__device__ __forceinline__ unsigned short f2h(float f) {
    return __half_as_ushort(__float2half_rn(f));
}
__device__ __forceinline__ float h2f(unsigned short s) {
    return __half2float(__ushort_as_half(s));
}

// ---------- p normalization ----------
__global__ void prep_p(const float* __restrict__ p0, const float* __restrict__ p1,
                       float* __restrict__ pn) {
    int t = threadIdx.x; // 64 threads, 1 wave
    float v0 = (t < 32) ? p0[t] : 0.f;
    float s0 = wred(v0 * v0);
    if (t < 32) pn[t] = v0 * rsqrtf(s0);
    float v1 = p1[t];
    float s1 = wred(v1 * v1);
    pn[32 + t] = v1 * rsqrtf(s1);
}

// ---------- f32 -> f16 conversion (8 elements/thread) ----------
__global__ void to_f16(const float* __restrict__ in, unsigned short* __restrict__ outp) {
    size_t i = ((size_t)blockIdx.x * 256 + threadIdx.x) * 8;
    float4 a = *(const float4*)(in + i);
    float4 b = *(const float4*)(in + i + 4);
    uint4 o;
    o.x = (unsigned)f2h(a.x) | ((unsigned)f2h(a.y) << 16);
    o.y = (unsigned)f2h(a.z) | ((unsigned)f2h(a.w) << 16);
    o.z = (unsigned)f2h(b.x) | ((unsigned)f2h(b.y) << 16);
    o.w = (unsigned)f2h(b.z) | ((unsigned)f2h(b.w) << 16);
    *(uint4*)(outp + i) = o;
}

// ---------- CSR build, XCD-privatized ----------
__global__ void count64(const int* __restrict__ ei, const float* __restrict__ ew,
                        unsigned long long* __restrict__ bins) {
    int e = blockIdx.x * 256 + threadIdx.x;
    int d = ei[EE + e];
    unsigned long long v = (1ULL << 40) |
        (unsigned long long)(unsigned int)__float2uint_rn(ew[e] * 16777216.0f);
    atomicAdd(&bins[(size_t)(blockIdx.x & 7) * NN + d], v);
}

__global__ void scan_block_bins(const unsigned long long* __restrict__ bins,
                                int* __restrict__ rowptr, int* __restrict__ bsum,
                                float* __restrict__ rsqd, float* __restrict__ invdeg) {
    __shared__ int sd[256];
    int t = threadIdx.x;
    int i = blockIdx.x * 256 + t;
    unsigned long long s = 0;
    #pragma unroll
    for (int x = 0; x < 8; x++) s += bins[(size_t)x * NN + i];
    int v = (int)(s >> 40);
    float deg = 1.f + (float)(s & ((1ULL << 40) - 1)) * (1.f / 16777216.f);
    rsqd[i] = rsqrtf(deg);
    invdeg[i] = 1.f / deg;
    sd[t] = v;
    __syncthreads();
    #pragma unroll
    for (int off = 1; off < 256; off <<= 1) {
        int add = (t >= off) ? sd[t - off] : 0;
        __syncthreads();
        sd[t] += add;
        __syncthreads();
    }
    rowptr[i] = sd[t] - v;
    if (t == 255) bsum[blockIdx.x] = sd[255];
}

__global__ void scan_partials(int* __restrict__ bsum) {
    __shared__ int sd[1024];
    int t = threadIdx.x;
    int v = bsum[t];
    sd[t] = v;
    __syncthreads();
    #pragma unroll
    for (int off = 1; off < 1024; off <<= 1) {
        int add = (t >= off) ? sd[t - off] : 0;
        __syncthreads();
        sd[t] += add;
        __syncthreads();
    }
    bsum[t] = sd[t] - v;
}

__global__ void scan_add(int* __restrict__ rowptr, const int* __restrict__ bsum) {
    int i = blockIdx.x * 256 + threadIdx.x;
    rowptr[i] += bsum[blockIdx.x];
    if (i == 0) rowptr[NN] = EE;
}

__global__ void cursor_init(const unsigned long long* __restrict__ bins,
                            const int* __restrict__ rowptr, int* __restrict__ cursor) {
    int n = blockIdx.x * 256 + threadIdx.x;
    int base = rowptr[n];
    #pragma unroll
    for (int x = 0; x < 8; x++) {
        cursor[(size_t)x * NN + n] = base;
        base += (int)(bins[(size_t)x * NN + n] >> 40);
    }
}

__global__ void scatter_edges(const int* __restrict__ ei, const float* __restrict__ ew,
                              const float* __restrict__ rsqd, int* __restrict__ cursor,
                              int2* __restrict__ evw) {
    int e = blockIdx.x * 256 + threadIdx.x;
    int s = ei[e];
    int d = ei[EE + e];
    float wt = ew[e] * rsqd[s];
    int pos = atomicAdd(&cursor[(size_t)(blockIdx.x & 7) * NN + d], 1);
    evw[pos] = make_int2(s, __float_as_int(wt));
}

// ---------- layer-0 scores ----------
__global__ void scores0_kernel(const float* __restrict__ x, const float* __restrict__ pn0,
                               float* __restrict__ scores) {
    __shared__ float p[32];
    if (threadIdx.x < 32) p[threadIdx.x] = pn0[threadIdx.x];
    __syncthreads();
    int n = blockIdx.x * 256 + threadIdx.x;
    const float4* xr = (const float4*)(x + (size_t)n * 32);
    float s = 0.f;
    #pragma unroll
    for (int j = 0; j < 8; j++) {
        float4 v = xr[j];
        s += v.x * p[j * 4] + v.y * p[j * 4 + 1] + v.z * p[j * 4 + 2] + v.w * p[j * 4 + 3];
    }
    scores[n] = s;
}

// ---------- per-graph top-7 ----------
__global__ void topk_kernel(const float* __restrict__ scores, float* __restrict__ topv,
                            int* __restrict__ topi) {
    int g = blockIdx.x;
    int t = threadIdx.x;
    float lv[KK];
    int li[KK];
    #pragma unroll
    for (int j = 0; j < KK; j++) { lv[j] = -INFINITY; li[j] = 0; }
    const float* sg = scores + (size_t)g * NPER;
    for (int it = 0; it < NPER / 256; ++it) {
        int idx = it * 256 + t;
        float v = sg[idx];
        if (v > lv[KK - 1]) {
            int j = KK - 1;
            while (j > 0 && lv[j - 1] < v) { lv[j] = lv[j - 1]; li[j] = li[j - 1]; j--; }
            lv[j] = v; li[j] = idx;
        }
    }
    __shared__ float sval[256];
    __shared__ int sidx[256];
    __shared__ int swin;
    int cons = 0;
    for (int r = 0; r < KK; r++) {
        sval[t] = (cons < KK) ? lv[cons] : -INFINITY;
        sidx[t] = t;
        __syncthreads();
        for (int s = 128; s > 0; s >>= 1) {
            if (t < s) {
                if (sval[t + s] > sval[t]) { sval[t] = sval[t + s]; sidx[t] = sidx[t + s]; }
            }
            __syncthreads();
        }
        if (t == 0) swin = sidx[0];
        __syncthreads();
        if (t == swin) {
            topv[g * KK + r] = lv[cons];
            topi[g * KK + r] = g * NPER + li[cons];
            cons++;
        }
        __syncthreads();
    }
}

// ---------- Z = mean_k tanh(s)*h[idx] (f32 source, layer 0) ----------
__global__ void z_kernel(const float* __restrict__ h, int din, const float* __restrict__ topv,
                         const int* __restrict__ topi, float* __restrict__ Z) {
    int b = blockIdx.x;
    int d = threadIdx.x;
    if (d >= din) return;
    float acc = 0.f;
    for (int j = 0; j < KK; j++) {
        acc += tanhf(topv[b * KK + j]) * h[(size_t)topi[b * KK + j] * din + d];
    }
    Z[b * din + d] = acc * (1.f / 7.f);
}

// ---------- Z from f16 source (layer 1) ----------
__global__ void z_kernel_h(const unsigned short* __restrict__ h, int din,
                           const float* __restrict__ topv, const int* __restrict__ topi,
                           float* __restrict__ Z) {
    int b = blockIdx.x;
    int d = threadIdx.x;
    if (d >= din) return;
    float acc = 0.f;
    for (int j = 0; j < KK; j++) {
        acc += tanhf(topv[b * KK + j]) * h2f(h[(size_t)topi[b * KK + j] * din + d]);
    }
    Z[b * din + d] = acc * (1.f / 7.f);
}

// ---------- GRU: ghl[j,b] = sum_k Whh[j,k]*gh[b,k] ----------
__global__ void gru_matvec(const float* __restrict__ Whh, const float* __restrict__ gh,
                           float* __restrict__ ghl, int P) {
    int t = threadIdx.x;
    int g = t >> 4, l16 = t & 15;
    int row = blockIdx.x * 16 + g;
    int k0 = blockIdx.y * 512;
    float acc[16];
    #pragma unroll
    for (int b = 0; b < 16; b++) acc[b] = 0.f;
    const float* wr = Whh + (size_t)row * P + k0 + l16 * 4;
    const float* gr = gh + k0 + l16 * 4;
    #pragma unroll 2
    for (int kk = 0; kk < 8; ++kk) {
        float4 a = *(const float4*)(wr + kk * 64);
        #pragma unroll
        for (int b = 0; b < 16; b++) {
            float4 gv = *(const float4*)(gr + (size_t)b * P + kk * 64);
            acc[b] += a.x * gv.x + a.y * gv.y + a.z * gv.z + a.w * gv.w;
        }
    }
    #pragma unroll
    for (int b = 0; b < 16; b++) {
        float v = acc[b];
        v += __shfl_xor(v, 1); v += __shfl_xor(v, 2);
        v += __shfl_xor(v, 4); v += __shfl_xor(v, 8);
        if (l16 == b) atomicAdd(&ghl[(size_t)row * 16 + b], v);
    }
}

// ---------- GRU gates + evolved-W mean ----------
__global__ void gate_kernel(const float* __restrict__ Wih, const float* __restrict__ bih,
                            const float* __restrict__ bhh, const float* __restrict__ gh,
                            const float* __restrict__ ghl, const float* __restrict__ Zg,
                            float* __restrict__ Wev, int P, int din) {
    __shared__ float Zs[16 * 64];
    int t = threadIdx.x;
    for (int idx = t; idx < 16 * din; idx += 256) Zs[idx] = Zg[idx];
    __syncthreads();
    int p = blockIdx.x * 256 + t;
    float br = bih[p], bz = bih[P + p], bn = bih[2 * P + p];
    float bhr = bhh[p], bhz = bhh[P + p], bhn = bhh[2 * P + p];
    const float* w_r = Wih + (size_t)p * din;
    const float* w_z = Wih + (size_t)(P + p) * din;
    const float* w_n = Wih + (size_t)(2 * P + p) * din;
    float wsum = 0.f;
    for (int b = 0; b < 16; b++) {
        float ir = br, iz = bz, inn = bn;
        for (int d = 0; d < din; ++d) {
            float zd = Zs[b * din + d];
            ir += w_r[d] * zd;
            iz += w_z[d] * zd;
            inn += w_n[d] * zd;
        }
        float hr = ghl[(size_t)p * 16 + b] + bhr;
        float hz = ghl[(size_t)(P + p) * 16 + b] + bhz;
        float hn = ghl[(size_t)(2 * P + p) * 16 + b] + bhn;
        float r = 1.f / (1.f + expf(-(ir + hr)));
        float z = 1.f / (1.f + expf(-(iz + hz)));
        float n = tanhf(inn + r * hn);
        float hprev = gh[(size_t)b * P + p];
        wsum += (1.f - z) * n + z * hprev;
    }
    Wev[p] = wsum * (1.f / 16.f);
}

// ---------- edge aggregation over f16 rows, TWO independent nodes per lane-group ----------
// Each (1<<LSH)-lane group owns nodes iA and iB=iA+NN/2: two independent 8-deep
// latency chains overlap (16 outstanding gathers/wave) regardless of degree skew.
// __launch_bounds__(256,6) gives the allocator headroom so it keeps the wide schedule.
template<int DIN, int LSH>
__global__ __launch_bounds__(256, 6) void agg_kernel(
                           const unsigned short* __restrict__ hin,
                           const int* __restrict__ rowptr, const int2* __restrict__ evw,
                           const float* __restrict__ rsqd, const float* __restrict__ invdeg,
                           float* __restrict__ agg, float* __restrict__ cc) {
    int t = threadIdx.x;
    int lane = t & ((1 << LSH) - 1);
    int iA = blockIdx.x * (256 >> LSH) + (t >> LSH);
    int iB = iA + NN / 2;
    int a0 = rowptr[iA], a1 = rowptr[iA + 1];
    int b0 = rowptr[iB], b1 = rowptr[iB + 1];
    float accA = 0.f, csA = 0.f, accB = 0.f, csB = 0.f;
    int rounds = (max(a1 - a0, b1 - b0) + 7) >> 3;
    for (int r2 = 0; r2 < rounds; ++r2) {
        int ea = a0 + r2 * 8, eb = b0 + r2 * 8;
        int2 evA[8], evB[8];
        #pragma unroll
        for (int j = 0; j < 8; j++)
            evA[j] = (ea + j < a1) ? evw[ea + j] : make_int2(iA, 0);
        #pragma unroll
        for (int j = 0; j < 8; j++)
            evB[j] = (eb + j < b1) ? evw[eb + j] : make_int2(iB, 0);
        float vA[8], vB[8];
        #pragma unroll
        for (int j = 0; j < 8; j++)
            vA[j] = h2f(hin[(size_t)evA[j].x * DIN + lane]);
        #pragma unroll
        for (int j = 0; j < 8; j++)
            vB[j] = h2f(hin[(size_t)evB[j].x * DIN + lane]);
        #pragma unroll
        for (int j = 0; j < 8; j++) {
            float nw = __int_as_float(evA[j].y);
            csA += nw;
            accA += nw * vA[j];
        }
        #pragma unroll
        for (int j = 0; j < 8; j++) {
            float nw = __int_as_float(evB[j].y);
            csB += nw;
            accB += nw * vB[j];
        }
    }
    {
        float rsi = rsqd[iA], idg = invdeg[iA];
        float r = accA * rsi + h2f(hin[(size_t)iA * DIN + lane]) * idg;
        agg[(size_t)iA * DIN + lane] = r;
        float cs = csA;
        #pragma unroll
        for (int o = (1 << LSH) >> 1; o > 0; o >>= 1) cs += __shfl_xor(cs, o);
        if (lane == 0) cc[iA] = cs * rsi + idg;
    }
    {
        float rsi = rsqd[iB], idg = invdeg[iB];
        float r = accB * rsi + h2f(hin[(size_t)iB * DIN + lane]) * idg;
        agg[(size_t)iB * DIN + lane] = r;
        float cs = csB;
        #pragma unroll
        for (int o = (1 << LSH) >> 1; o > 0; o >>= 1) cs += __shfl_xor(cs, o);
        if (lane == 0) cc[iB] = cs * rsi + idg;
    }
}

// ---------- post kernels: 1 wave = 64-node tile, lane = outdim ----------
__global__ __launch_bounds__(64) void post0_kernel(
    const float* __restrict__ agg, const float* __restrict__ cc,
    const float* __restrict__ Wev, const float* __restrict__ gcnb,
    const float* __restrict__ lng, const float* __restrict__ lnb,
    const float* __restrict__ pn1, unsigned short* __restrict__ h1h,
    float* __restrict__ scores) {
    __shared__ float tile[64 * TPAD];
    const int lane = threadIdx.x;
    const int tb = blockIdx.x * 64;
    const int j = lane & 15, q = lane >> 4;
    float v0[16], v1[16], v2[16], v3[16];
    #pragma unroll
    for (int k = 0; k < 16; k++) { v0[k] = 0.f; v1[k] = 0.f; v2[k] = 0.f; v3[k] = 0.f; }
    for (int db = 0; db < 8; ++db) {
        float wc0 = Wev[(db * 4 + 0) * 64 + lane];
        float wc1 = Wev[(db * 4 + 1) * 64 + lane];
        float wc2 = Wev[(db * 4 + 2) * 64 + lane];
        float wc3 = Wev[(db * 4 + 3) * 64 + lane];
        #pragma unroll
        for (int k = 0; k < 16; k++) {
            float4 a = *(const float4*)(agg + (size_t)(tb + k) * 32 + db * 4);
            v0[k] += a.x * wc0 + a.y * wc1 + a.z * wc2 + a.w * wc3;
        }
        #pragma unroll
        for (int k = 0; k < 16; k++) {
            float4 a = *(const float4*)(agg + (size_t)(tb + 16 + k) * 32 + db * 4);
            v1[k] += a.x * wc0 + a.y * wc1 + a.z * wc2 + a.w * wc3;
        }
        #pragma unroll
        for (int k = 0; k < 16; k++) {
            float4 a = *(const float4*)(agg + (size_t)(tb + 32 + k) * 32 + db * 4);
            v2[k] += a.x * wc0 + a.y * wc1 + a.z * wc2 + a.w * wc3;
        }
        #pragma unroll
        for (int k = 0; k < 16; k++) {
            float4 a = *(const float4*)(agg + (size_t)(tb + 48 + k) * 32 + db * 4);
            v3[k] += a.x * wc0 + a.y * wc1 + a.z * wc2 + a.w * wc3;
        }
    }
    float gL = gcnb[lane];
    float lgv[16], lbv[16], pnv[16];
    #pragma unroll
    for (int r = 0; r < 16; r++) {
        lgv[r] = lng[q * 16 + r];
        lbv[r] = lnb[q * 16 + r];
        pnv[r] = pn1[q * 16 + r];
    }
    float* trow = tile + lane * TPAD;
    auto do_chunk = [&](float (&VV)[16], int C) {
        __syncthreads();
        #pragma unroll
        for (int k = 0; k < 16; k++) trow[k] = VV[k] + gL * cc[tb + C * 16 + k];
        __syncthreads();
        float av[16];
        #pragma unroll
        for (int r = 0; r < 16; r++) av[r] = tile[(q * 16 + r) * TPAD + j];
        float s1 = 0.f, s2 = 0.f;
        #pragma unroll
        for (int r = 0; r < 16; r++) { s1 += av[r]; s2 += av[r] * av[r]; }
        s1 += __shfl_xor(s1, 16); s1 += __shfl_xor(s1, 32);
        s2 += __shfl_xor(s2, 16); s2 += __shfl_xor(s2, 32);
        float mu = s1 * (1.f / 64.f);
        float rstd = rsqrtf(s2 * (1.f / 64.f) - mu * mu + 1e-5f);
        float hv[16];
        float sc = 0.f;
        #pragma unroll
        for (int r = 0; r < 16; r++) {
            hv[r] = fmaxf((av[r] - mu) * rstd * lgv[r] + lbv[r], 0.f);
            sc += hv[r] * pnv[r];
        }
        int node = tb + C * 16 + j;
        uint4 o0, o1;
        o0.x = (unsigned)f2h(hv[0])  | ((unsigned)f2h(hv[1])  << 16);
        o0.y = (unsigned)f2h(hv[2])  | ((unsigned)f2h(hv[3])  << 16);
        o0.z = (unsigned)f2h(hv[4])  | ((unsigned)f2h(hv[5])  << 16);
        o0.w = (unsigned)f2h(hv[6])  | ((unsigned)f2h(hv[7])  << 16);
        o1.x = (unsigned)f2h(hv[8])  | ((unsigned)f2h(hv[9])  << 16);
        o1.y = (unsigned)f2h(hv[10]) | ((unsigned)f2h(hv[11]) << 16);
        o1.z = (unsigned)f2h(hv[12]) | ((unsigned)f2h(hv[13]) << 16);
        o1.w = (unsigned)f2h(hv[14]) | ((unsigned)f2h(hv[15]) << 16);
        *(uint4*)(h1h + (size_t)node * 64 + q * 16) = o0;
        *(uint4*)(h1h + (size_t)node * 64 + q * 16 + 8) = o1;
        sc += __shfl_xor(sc, 16); sc += __shfl_xor(sc, 32);
        if (q == 0) scores[node] = sc;
    };
    do_chunk(v0, 0); do_chunk(v1, 1); do_chunk(v2, 2); do_chunk(v3, 3);
}

__global__ __launch_bounds__(64) void post1_kernel(
    const float* __restrict__ agg, const float* __restrict__ cc,
    const float* __restrict__ Wev, const float* __restrict__ gcnb,
    const float* __restrict__ lng, const float* __restrict__ lnb,
    const float* __restrict__ Wp, const float* __restrict__ bp,
    float* __restrict__ out) {
    __shared__ float tile[64 * TPAD];
    const int lane = threadIdx.x;
    const int tb = blockIdx.x * 64;
    const int j = lane & 15, q = lane >> 4;
    float v0[16], v1[16], v2[16], v3[16];
    #pragma unroll
    for (int k = 0; k < 16; k++) { v0[k] = 0.f; v1[k] = 0.f; v2[k] = 0.f; v3[k] = 0.f; }
    for (int db = 0; db < 16; ++db) {
        float wc0 = Wev[(db * 4 + 0) * 64 + lane];
        float wc1 = Wev[(db * 4 + 1) * 64 + lane];
        float wc2 = Wev[(db * 4 + 2) * 64 + lane];
        float wc3 = Wev[(db * 4 + 3) * 64 + lane];
        #pragma unroll
        for (int k = 0; k < 16; k++) {
            float4 a = *(const float4*)(agg + (size_t)(tb + k) * 64 + db * 4);
            v0[k] += a.x * wc0 + a.y * wc1 + a.z * wc2 + a.w * wc3;
        }
        #pragma unroll
        for (int k = 0; k < 16; k++) {
            float4 a = *(const float4*)(agg + (size_t)(tb + 16 + k) * 64 + db * 4);
            v1[k] += a.x * wc0 + a.y * wc1 + a.z * wc2 + a.w * wc3;
        }
        #pragma unroll
        for (int k = 0; k < 16; k++) {
            float4 a = *(const float4*)(agg + (size_t)(tb + 32 + k) * 64 + db * 4);
            v2[k] += a.x * wc0 + a.y * wc1 + a.z * wc2 + a.w * wc3;
        }
        #pragma unroll
        for (int k = 0; k < 16; k++) {
            float4 a = *(const float4*)(agg + (size_t)(tb + 48 + k) * 64 + db * 4);
            v3[k] += a.x * wc0 + a.y * wc1 + a.z * wc2 + a.w * wc3;
        }
    }
    float gL = gcnb[lane];
    float lgv[16], lbv[16];
    #pragma unroll
    for (int r = 0; r < 16; r++) {
        lgv[r] = lng[q * 16 + r];
        lbv[r] = lnb[q * 16 + r];
    }
    float bpv[10];
    #pragma unroll
    for (int t2 = 0; t2 < 10; t2++) bpv[t2] = bp[t2];
    float* trow = tile + lane * TPAD;
    auto do_chunk = [&](float (&VV)[16], int C) {
        __syncthreads();
        #pragma unroll
        for (int k = 0; k < 16; k++) trow[k] = VV[k] + gL * cc[tb + C * 16 + k];
        __syncthreads();
        float av[16];
        #pragma unroll
        for (int r = 0; r < 16; r++) av[r] = tile[(q * 16 + r) * TPAD + j];
        float s1 = 0.f, s2 = 0.f;
        #pragma unroll
        for (int r = 0; r < 16; r++) { s1 += av[r]; s2 += av[r] * av[r]; }
        s1 += __shfl_xor(s1, 16); s1 += __shfl_xor(s1, 32);
        s2 += __shfl_xor(s2, 16); s2 += __shfl_xor(s2, 32);
        float mu = s1 * (1.f / 64.f);
        float rstd = rsqrtf(s2 * (1.f / 64.f) - mu * mu + 1e-5f);
        float hv[16];
        #pragma unroll
        for (int r = 0; r < 16; r++)
            hv[r] = fmaxf((av[r] - mu) * rstd * lgv[r] + lbv[r], 0.f);
        float oa[10];
        #pragma unroll
        for (int t2 = 0; t2 < 10; t2++) oa[t2] = 0.f;
        #pragma unroll
        for (int r = 0; r < 16; r++) {
            const float* wpb = Wp + (size_t)(q * 16 + r) * 2;
            float2 w0 = *(const float2*)(wpb);
            float2 w1 = *(const float2*)(wpb + 128);
            float2 w2 = *(const float2*)(wpb + 256);
            float2 w3 = *(const float2*)(wpb + 384);
            float2 w4 = *(const float2*)(wpb + 512);
            oa[0] += hv[r] * w0.x; oa[1] += hv[r] * w0.y;
            oa[2] += hv[r] * w1.x; oa[3] += hv[r] * w1.y;
            oa[4] += hv[r] * w2.x; oa[5] += hv[r] * w2.y;
            oa[6] += hv[r] * w3.x; oa[7] += hv[r] * w3.y;
            oa[8] += hv[r] * w4.x; oa[9] += hv[r] * w4.y;
        }
        #pragma unroll
        for (int t2 = 0; t2 < 10; t2++) {
            oa[t2] += __shfl_xor(oa[t2], 16);
            oa[t2] += __shfl_xor(oa[t2], 32);
        }
        if (q == 0) {
            int node = tb + C * 16 + j;
            #pragma unroll
            for (int t2 = 0; t2 < 10; t2++) out[(size_t)node * 10 + t2] = oa[t2] + bpv[t2];
        }
    };
    do_chunk(v0, 0); do_chunk(v1, 1); do_chunk(v2, 2); do_chunk(v3, 3);
}

extern "C" void kernel_launch(void* const* d_in, const int* in_sizes, int n_in,
                              void* d_out, int out_size, void* d_ws, size_t ws_size,
                              hipStream_t stream) {
    const float* x     = (const float*)d_in[0];
    const int*   ei    = (const int*)d_in[1];
    const float* ew    = (const float*)d_in[2];
    const float* p0    = (const float*)d_in[5];
    const float* p1    = (const float*)d_in[6];
    const float* Wih0  = (const float*)d_in[7];
    const float* Whh0  = (const float*)d_in[8];
    const float* bih0  = (const float*)d_in[9];
    const float* bhh0  = (const float*)d_in[10];
    const float* Wih1  = (const float*)d_in[11];
    const float* Whh1  = (const float*)d_in[12];
    const float* bih1  = (const float*)d_in[13];
    const float* bhh1  = (const float*)d_in[14];
    const float* gruh0 = (const float*)d_in[15];
    const float* gruh1 = (const float*)d_in[16];
    const float* gcnb0 = (const float*)d_in[17];
    const float* gcnb1 = (const float*)d_in[18];
    const float* lng0  = (const float*)d_in[19];
    const float* lnb0  = (const float*)d_in[20];
    const float* lng1  = (const float*)d_in[21];
    const float* lnb1  = (const float*)d_in[22];
    const float* Wp    = (const float*)d_in[23];
    const float* bp    = (const float*)d_in[24];
    float* out = (float*)d_out;

    // workspace carve
    char* w = (char*)d_ws;
    size_t off = 0;
    auto alloc = [&](size_t bytes) -> void* {
        void* p = w + off;
        off += (bytes + 255) & ~(size_t)255;
        return p;
    };
    int*   rowptr = (int*)alloc((NN + 1) * sizeof(int));
    int2*  evw    = (int2*)alloc((size_t)EE * sizeof(int2));
    float* rsqd   = (float*)alloc(NN * sizeof(float));
    float* invdeg = (float*)alloc(NN * sizeof(float));
    float* scores = (float*)alloc(NN * sizeof(float));
    float* topv   = (float*)alloc(NG * KK * sizeof(float));
    int*   topi   = (int*)alloc(NG * KK * sizeof(int));
    float* Z      = (float*)alloc(16 * 64 * sizeof(float));
    float* ghl    = (float*)alloc((size_t)12288 * 16 * sizeof(float));
    float* Wev    = (float*)alloc(4096 * sizeof(float));
    float* cc     = (float*)alloc(NN * sizeof(float));
    float* agg    = (float*)alloc((size_t)NN * 64 * sizeof(float));
    unsigned short* xh  = (unsigned short*)alloc((size_t)NN * 32 * sizeof(unsigned short));
    unsigned short* h1h = (unsigned short*)alloc((size_t)NN * 64 * sizeof(unsigned short));
    float* pn     = (float*)alloc(96 * sizeof(float));
    int*   bsum   = (int*)alloc(1024 * sizeof(int));

    // bins64 (16 MB) + cursor (8 MB) alias into agg's 67 MB (dead before agg is written)
    unsigned long long* bins64 = (unsigned long long*)agg;
    int* cursor = (int*)((char*)agg + (size_t)8 * NN * sizeof(unsigned long long));

    // --- CSR build (shared by both layers), XCD-privatized ---
    hipMemsetAsync(bins64, 0, (size_t)8 * NN * sizeof(unsigned long long), stream);
    prep_p<<<1, 64, 0, stream>>>(p0, p1, pn);
    to_f16<<<NN * 32 / 8 / 256, 256, 0, stream>>>(x, xh);
    count64<<<EE / 256, 256, 0, stream>>>(ei, ew, bins64);
    scan_block_bins<<<NN / 256, 256, 0, stream>>>(bins64, rowptr, bsum, rsqd, invdeg);
    scan_partials<<<1, 1024, 0, stream>>>(bsum);
    scan_add<<<NN / 256, 256, 0, stream>>>(rowptr, bsum);
    cursor_init<<<NN / 256, 256, 0, stream>>>(bins64, rowptr, cursor);
    scatter_edges<<<EE / 256, 256, 0, stream>>>(ei, ew, rsqd, cursor, evw);

    // --- layer 0 ---
    scores0_kernel<<<NN / 256, 256, 0, stream>>>(x, pn, scores);
    topk_kernel<<<NG, 256, 0, stream>>>(scores, topv, topi);
    z_kernel<<<NG, 32, 0, stream>>>(x, 32, topv, topi, Z);
    hipMemsetAsync(ghl, 0, (size_t)6144 * 16 * sizeof(float), stream);
    gru_matvec<<<dim3(6144 / 16, 4), 256, 0, stream>>>(Whh0, gruh0, ghl, 2048);
    gate_kernel<<<2048 / 256, 256, 0, stream>>>(Wih0, bih0, bhh0, gruh0, ghl, Z, Wev, 2048, 32);
    agg_kernel<32, 5><<<(NN / 2) / 8, 256, 0, stream>>>(xh, rowptr, evw, rsqd, invdeg, agg, cc);
    post0_kernel<<<NN / 64, 64, 0, stream>>>(agg, cc, Wev, gcnb0, lng0, lnb0, pn + 32, h1h, scores);

    // --- layer 1 ---
    topk_kernel<<<NG, 256, 0, stream>>>(scores, topv, topi);
    z_kernel_h<<<NG, 64, 0, stream>>>(h1h, 64, topv, topi, Z);
    hipMemsetAsync(ghl, 0, (size_t)12288 * 16 * sizeof(float), stream);
    gru_matvec<<<dim3(12288 / 16, 8), 256, 0, stream>>>(Whh1, gruh1, ghl, 4096);
    gate_kernel<<<4096 / 256, 256, 0, stream>>>(Wih1, bih1, bhh1, gruh1, ghl, Z, Wev, 4096, 64);
    agg_kernel<64, 6><<<(NN / 2) / 4, 256, 0, stream>>>(h1h, rowptr, evw, rsqd, invdeg, agg, cc);
    post1_kernel<<<NN / 64, 64, 0, stream>>>(agg, cc, Wev, gcnb1, lng1, lnb1, Wp, bp, out);
}

// Round 10
// 1741.875 us; speedup vs baseline: 1.0759x; 1.0759x over previous
//
#include <hip/hip_runtime.h>
#include <hip/hip_bf16.h>
#include <hip/hip_fp16.h>

#define NN 262144
#define EE 4194304
#define NG 16
#define NPER 16384
#define KK 7
#define TPAD 20

typedef unsigned long long u64;

__device__ __forceinline__ float wred(float v) {
    #pragma unroll
    for (int o = 32; o > 0; o >>= 1) v += __shfl_xor(v, o);
    return v;
}

__device__ __forceinline__ unsigned short f2h(float f) {
    return __half_as_ushort(__float2half_rn(f));
}
__device__ __forceinline__ float h2f(unsigned short s) {
    return __half2float(__ushort_as_half(s));
}

// real XCD id (exact privatization; blockIdx%8 is only a guess) [m09]
__device__ __forceinline__ int xcd_id() {
    unsigned x;
    asm volatile("s_getreg_b32 %0, hwreg(HW_REG_XCC_ID)" : "=s"(x));
    return (int)(x & 7);
}

// ---------- p normalization ----------
__global__ void prep_p(const float* __restrict__ p0, const float* __restrict__ p1,
                       float* __restrict__ pn) {
    int t = threadIdx.x; // 64 threads, 1 wave
    float v0 = (t < 32) ? p0[t] : 0.f;
    float s0 = wred(v0 * v0);
    if (t < 32) pn[t] = v0 * rsqrtf(s0);
    float v1 = p1[t];
    float s1 = wred(v1 * v1);
    pn[32 + t] = v1 * rsqrtf(s1);
}

// ---------- f32 -> f16 conversion (8 elements/thread) ----------
__global__ void to_f16(const float* __restrict__ in, unsigned short* __restrict__ outp) {
    size_t i = ((size_t)blockIdx.x * 256 + threadIdx.x) * 8;
    float4 a = *(const float4*)(in + i);
    float4 b = *(const float4*)(in + i + 4);
    uint4 o;
    o.x = (unsigned)f2h(a.x) | ((unsigned)f2h(a.y) << 16);
    o.y = (unsigned)f2h(a.z) | ((unsigned)f2h(a.w) << 16);
    o.z = (unsigned)f2h(b.x) | ((unsigned)f2h(b.y) << 16);
    o.w = (unsigned)f2h(b.z) | ((unsigned)f2h(b.w) << 16);
    *(uint4*)(outp + i) = o;
}

// ---------- CSR build, XCD-exact privatization ----------
__global__ void count64(const int* __restrict__ ei, const float* __restrict__ ew,
                        u64* __restrict__ bins) {
    int e = blockIdx.x * 256 + threadIdx.x;
    int d = ei[EE + e];
    u64 v = (1ULL << 40) |
        (u64)(unsigned int)__float2uint_rn(ew[e] * 16777216.0f);
    atomicAdd(&bins[(size_t)xcd_id() * NN + d], v);
}

// per-block scans: global count (rowptr) + 8 per-slice counts (c2)
__global__ void scan1(const u64* __restrict__ bins, int* __restrict__ rowptr,
                      int* __restrict__ bsum, int* __restrict__ bsum8,
                      int* __restrict__ c2, float* __restrict__ rsqd,
                      float* __restrict__ invdeg) {
    __shared__ int sd[256];
    int t = threadIdx.x;
    int i = blockIdx.x * 256 + t;
    int cnt[8];
    u64 s = 0;
    #pragma unroll
    for (int x = 0; x < 8; x++) {
        u64 b = bins[(size_t)x * NN + i];
        cnt[x] = (int)(b >> 40);
        s += b;
    }
    int v = (int)(s >> 40);
    float deg = 1.f + (float)(s & ((1ULL << 40) - 1)) * (1.f / 16777216.f);
    rsqd[i] = rsqrtf(deg);
    invdeg[i] = 1.f / deg;
    // scan total
    sd[t] = v;
    __syncthreads();
    #pragma unroll
    for (int off = 1; off < 256; off <<= 1) {
        int add = (t >= off) ? sd[t - off] : 0;
        __syncthreads();
        sd[t] += add;
        __syncthreads();
    }
    rowptr[i] = sd[t] - v;
    if (t == 255) bsum[blockIdx.x] = sd[255];
    // scan each slice count
    for (int x = 0; x < 8; x++) {
        __syncthreads();
        sd[t] = cnt[x];
        __syncthreads();
        #pragma unroll
        for (int off = 1; off < 256; off <<= 1) {
            int add = (t >= off) ? sd[t - off] : 0;
            __syncthreads();
            sd[t] += add;
            __syncthreads();
        }
        c2[(size_t)x * NN + i] = sd[t] - cnt[x];
        if (t == 255) bsum8[x * 1024 + blockIdx.x] = sd[255];
    }
}

// single block: scan the 1024 block-sums for global and for each slice (with running base)
__global__ void scan2(int* __restrict__ bsum, int* __restrict__ bsum8) {
    __shared__ int sd[1024];
    __shared__ int base;
    int t = threadIdx.x;
    // global
    int v = bsum[t];
    sd[t] = v;
    __syncthreads();
    #pragma unroll
    for (int off = 1; off < 1024; off <<= 1) {
        int add = (t >= off) ? sd[t - off] : 0;
        __syncthreads();
        sd[t] += add;
        __syncthreads();
    }
    bsum[t] = sd[t] - v;
    if (t == 0) base = 0;
    __syncthreads();
    for (int x = 0; x < 8; x++) {
        int vx = bsum8[x * 1024 + t];
        __syncthreads();
        sd[t] = vx;
        __syncthreads();
        #pragma unroll
        for (int off = 1; off < 1024; off <<= 1) {
            int add = (t >= off) ? sd[t - off] : 0;
            __syncthreads();
            sd[t] += add;
            __syncthreads();
        }
        bsum8[x * 1024 + t] = sd[t] - vx + base;
        __syncthreads();
        if (t == 0) base += sd[1023];
        __syncthreads();
    }
}

__global__ void scan3(int* __restrict__ rowptr, const int* __restrict__ bsum,
                      const int* __restrict__ bsum8, int* __restrict__ c2,
                      int* __restrict__ c2s) {
    int t = threadIdx.x;
    int i = blockIdx.x * 256 + t;
    rowptr[i] += bsum[blockIdx.x];
    if (i == 0) rowptr[NN] = EE;
    #pragma unroll
    for (int x = 0; x < 8; x++) {
        int p = c2[(size_t)x * NN + i] + bsum8[x * 1024 + blockIdx.x];
        c2[(size_t)x * NN + i] = p;
        c2s[(size_t)x * NN + i] = p;
    }
}

// scatter into slice-contiguous evw_s: every line written by exactly one XCD
__global__ void scatter_edges(const int* __restrict__ ei, const float* __restrict__ ew,
                              const float* __restrict__ rsqd, int* __restrict__ c2,
                              int2* __restrict__ evw_s) {
    int e = blockIdx.x * 256 + threadIdx.x;
    int s = ei[e];
    int d = ei[EE + e];
    float wt = ew[e] * rsqd[s];
    int pos = atomicAdd(&c2[(size_t)xcd_id() * NN + d], 1);
    evw_s[pos] = make_int2(s, __float_as_int(wt));
}

// compaction: slice-major -> node-major; coalesced reads and writes
__global__ void compact(const int* __restrict__ rowptr, const int* __restrict__ c2s,
                        const int* __restrict__ c2, const int2* __restrict__ evw_s,
                        int2* __restrict__ evw) {
    int d = blockIdx.x * 256 + threadIdx.x;
    int wpos = rowptr[d];
    #pragma unroll
    for (int x = 0; x < 8; x++) {
        int b0 = c2s[(size_t)x * NN + d];
        int b1 = c2[(size_t)x * NN + d];
        for (int e = b0; e < b1; ++e) evw[wpos++] = evw_s[e];
    }
}

// ---------- layer-0 scores ----------
__global__ void scores0_kernel(const float* __restrict__ x, const float* __restrict__ pn0,
                               float* __restrict__ scores) {
    __shared__ float p[32];
    if (threadIdx.x < 32) p[threadIdx.x] = pn0[threadIdx.x];
    __syncthreads();
    int n = blockIdx.x * 256 + threadIdx.x;
    const float4* xr = (const float4*)(x + (size_t)n * 32);
    float s = 0.f;
    #pragma unroll
    for (int j = 0; j < 8; j++) {
        float4 v = xr[j];
        s += v.x * p[j * 4] + v.y * p[j * 4 + 1] + v.z * p[j * 4 + 2] + v.w * p[j * 4 + 3];
    }
    scores[n] = s;
}

// ---------- per-graph top-7 ----------
__global__ void topk_kernel(const float* __restrict__ scores, float* __restrict__ topv,
                            int* __restrict__ topi) {
    int g = blockIdx.x;
    int t = threadIdx.x;
    float lv[KK];
    int li[KK];
    #pragma unroll
    for (int j = 0; j < KK; j++) { lv[j] = -INFINITY; li[j] = 0; }
    const float* sg = scores + (size_t)g * NPER;
    for (int it = 0; it < NPER / 256; ++it) {
        int idx = it * 256 + t;
        float v = sg[idx];
        if (v > lv[KK - 1]) {
            int j = KK - 1;
            while (j > 0 && lv[j - 1] < v) { lv[j] = lv[j - 1]; li[j] = li[j - 1]; j--; }
            lv[j] = v; li[j] = idx;
        }
    }
    __shared__ float sval[256];
    __shared__ int sidx[256];
    __shared__ int swin;
    int cons = 0;
    for (int r = 0; r < KK; r++) {
        sval[t] = (cons < KK) ? lv[cons] : -INFINITY;
        sidx[t] = t;
        __syncthreads();
        for (int s = 128; s > 0; s >>= 1) {
            if (t < s) {
                if (sval[t + s] > sval[t]) { sval[t] = sval[t + s]; sidx[t] = sidx[t + s]; }
            }
            __syncthreads();
        }
        if (t == 0) swin = sidx[0];
        __syncthreads();
        if (t == swin) {
            topv[g * KK + r] = lv[cons];
            topi[g * KK + r] = g * NPER + li[cons];
            cons++;
        }
        __syncthreads();
    }
}

// ---------- Z = mean_k tanh(s)*h[idx] (f32 source, layer 0) ----------
__global__ void z_kernel(const float* __restrict__ h, int din, const float* __restrict__ topv,
                         const int* __restrict__ topi, float* __restrict__ Z) {
    int b = blockIdx.x;
    int d = threadIdx.x;
    if (d >= din) return;
    float acc = 0.f;
    for (int j = 0; j < KK; j++) {
        acc += tanhf(topv[b * KK + j]) * h[(size_t)topi[b * KK + j] * din + d];
    }
    Z[b * din + d] = acc * (1.f / 7.f);
}

// ---------- Z from f16 source (layer 1) ----------
__global__ void z_kernel_h(const unsigned short* __restrict__ h, int din,
                           const float* __restrict__ topv, const int* __restrict__ topi,
                           float* __restrict__ Z) {
    int b = blockIdx.x;
    int d = threadIdx.x;
    if (d >= din) return;
    float acc = 0.f;
    for (int j = 0; j < KK; j++) {
        acc += tanhf(topv[b * KK + j]) * h2f(h[(size_t)topi[b * KK + j] * din + d]);
    }
    Z[b * din + d] = acc * (1.f / 7.f);
}

// ---------- GRU: ghl[j,b] = sum_k Whh[j,k]*gh[b,k] ----------
__global__ void gru_matvec(const float* __restrict__ Whh, const float* __restrict__ gh,
                           float* __restrict__ ghl, int P) {
    int t = threadIdx.x;
    int g = t >> 4, l16 = t & 15;
    int row = blockIdx.x * 16 + g;
    int k0 = blockIdx.y * 512;
    float acc[16];
    #pragma unroll
    for (int b = 0; b < 16; b++) acc[b] = 0.f;
    const float* wr = Whh + (size_t)row * P + k0 + l16 * 4;
    const float* gr = gh + k0 + l16 * 4;
    #pragma unroll 2
    for (int kk = 0; kk < 8; ++kk) {
        float4 a = *(const float4*)(wr + kk * 64);
        #pragma unroll
        for (int b = 0; b < 16; b++) {
            float4 gv = *(const float4*)(gr + (size_t)b * P + kk * 64);
            acc[b] += a.x * gv.x + a.y * gv.y + a.z * gv.z + a.w * gv.w;
        }
    }
    #pragma unroll
    for (int b = 0; b < 16; b++) {
        float v = acc[b];
        v += __shfl_xor(v, 1); v += __shfl_xor(v, 2);
        v += __shfl_xor(v, 4); v += __shfl_xor(v, 8);
        if (l16 == b) atomicAdd(&ghl[(size_t)row * 16 + b], v);
    }
}

// ---------- GRU gates + evolved-W mean ----------
__global__ void gate_kernel(const float* __restrict__ Wih, const float* __restrict__ bih,
                            const float* __restrict__ bhh, const float* __restrict__ gh,
                            const float* __restrict__ ghl, const float* __restrict__ Zg,
                            float* __restrict__ Wev, int P, int din) {
    __shared__ float Zs[16 * 64];
    int t = threadIdx.x;
    for (int idx = t; idx < 16 * din; idx += 256) Zs[idx] = Zg[idx];
    __syncthreads();
    int p = blockIdx.x * 256 + t;
    float br = bih[p], bz = bih[P + p], bn = bih[2 * P + p];
    float bhr = bhh[p], bhz = bhh[P + p], bhn = bhh[2 * P + p];
    const float* w_r = Wih + (size_t)p * din;
    const float* w_z = Wih + (size_t)(P + p) * din;
    const float* w_n = Wih + (size_t)(2 * P + p) * din;
    float wsum = 0.f;
    for (int b = 0; b < 16; b++) {
        float ir = br, iz = bz, inn = bn;
        for (int d = 0; d < din; ++d) {
            float zd = Zs[b * din + d];
            ir += w_r[d] * zd;
            iz += w_z[d] * zd;
            inn += w_n[d] * zd;
        }
        float hr = ghl[(size_t)p * 16 + b] + bhr;
        float hz = ghl[(size_t)(P + p) * 16 + b] + bhz;
        float hn = ghl[(size_t)(2 * P + p) * 16 + b] + bhn;
        float r = 1.f / (1.f + expf(-(ir + hr)));
        float z = 1.f / (1.f + expf(-(iz + hz)));
        float n = tanhf(inn + r * hn);
        float hprev = gh[(size_t)b * P + p];
        wsum += (1.f - z) * n + z * hprev;
    }
    Wev[p] = wsum * (1.f / 16.f);
}

// ---------- edge aggregation over f16 rows (R7 version: 8-deep, ~24 VGPR) ----------
template<int DIN, int LSH>
__global__ void agg_kernel(const unsigned short* __restrict__ hin,
                           const int* __restrict__ rowptr, const int2* __restrict__ evw,
                           const float* __restrict__ rsqd, const float* __restrict__ invdeg,
                           float* __restrict__ agg, float* __restrict__ cc) {
    int t = threadIdx.x;
    int lane = t & ((1 << LSH) - 1);
    int i = blockIdx.x * (256 >> LSH) + (t >> LSH);
    int e0 = rowptr[i], e1 = rowptr[i + 1];
    float acc = 0.f, csum = 0.f;
    for (int e = e0; e < e1; e += 8) {
        int2 ev[8];
        #pragma unroll
        for (int j = 0; j < 8; j++) {
            ev[j] = (e + j < e1) ? evw[e + j] : make_int2(i, 0);
        }
        float v[8];
        #pragma unroll
        for (int j = 0; j < 8; j++) {
            v[j] = h2f(hin[(size_t)ev[j].x * DIN + lane]);
        }
        #pragma unroll
        for (int j = 0; j < 8; j++) {
            float nw = __int_as_float(ev[j].y);
            csum += nw;
            acc += nw * v[j];
        }
    }
    float rsi = rsqd[i];
    float idg = invdeg[i];
    float r = acc * rsi + h2f(hin[(size_t)i * DIN + lane]) * idg;
    agg[(size_t)i * DIN + lane] = r;
    #pragma unroll
    for (int o = (1 << LSH) >> 1; o > 0; o >>= 1) csum += __shfl_xor(csum, o);
    if (lane == 0) cc[i] = csum * rsi + idg;
}

// ---------- post kernels: 1 wave = 64-node tile, lane = outdim ----------
__global__ __launch_bounds__(64) void post0_kernel(
    const float* __restrict__ agg, const float* __restrict__ cc,
    const float* __restrict__ Wev, const float* __restrict__ gcnb,
    const float* __restrict__ lng, const float* __restrict__ lnb,
    const float* __restrict__ pn1, unsigned short* __restrict__ h1h,
    float* __restrict__ scores) {
    __shared__ float tile[64 * TPAD];
    const int lane = threadIdx.x;
    const int tb = blockIdx.x * 64;
    const int j = lane & 15, q = lane >> 4;
    float v0[16], v1[16], v2[16], v3[16];
    #pragma unroll
    for (int k = 0; k < 16; k++) { v0[k] = 0.f; v1[k] = 0.f; v2[k] = 0.f; v3[k] = 0.f; }
    for (int db = 0; db < 8; ++db) {
        float wc0 = Wev[(db * 4 + 0) * 64 + lane];
        float wc1 = Wev[(db * 4 + 1) * 64 + lane];
        float wc2 = Wev[(db * 4 + 2) * 64 + lane];
        float wc3 = Wev[(db * 4 + 3) * 64 + lane];
        #pragma unroll
        for (int k = 0; k < 16; k++) {
            float4 a = *(const float4*)(agg + (size_t)(tb + k) * 32 + db * 4);
            v0[k] += a.x * wc0 + a.y * wc1 + a.z * wc2 + a.w * wc3;
        }
        #pragma unroll
        for (int k = 0; k < 16; k++) {
            float4 a = *(const float4*)(agg + (size_t)(tb + 16 + k) * 32 + db * 4);
            v1[k] += a.x * wc0 + a.y * wc1 + a.z * wc2 + a.w * wc3;
        }
        #pragma unroll
        for (int k = 0; k < 16; k++) {
            float4 a = *(const float4*)(agg + (size_t)(tb + 32 + k) * 32 + db * 4);
            v2[k] += a.x * wc0 + a.y * wc1 + a.z * wc2 + a.w * wc3;
        }
        #pragma unroll
        for (int k = 0; k < 16; k++) {
            float4 a = *(const float4*)(agg + (size_t)(tb + 48 + k) * 32 + db * 4);
            v3[k] += a.x * wc0 + a.y * wc1 + a.z * wc2 + a.w * wc3;
        }
    }
    float gL = gcnb[lane];
    float lgv[16], lbv[16], pnv[16];
    #pragma unroll
    for (int r = 0; r < 16; r++) {
        lgv[r] = lng[q * 16 + r];
        lbv[r] = lnb[q * 16 + r];
        pnv[r] = pn1[q * 16 + r];
    }
    float* trow = tile + lane * TPAD;
    auto do_chunk = [&](float (&VV)[16], int C) {
        __syncthreads();
        #pragma unroll
        for (int k = 0; k < 16; k++) trow[k] = VV[k] + gL * cc[tb + C * 16 + k];
        __syncthreads();
        float av[16];
        #pragma unroll
        for (int r = 0; r < 16; r++) av[r] = tile[(q * 16 + r) * TPAD + j];
        float s1 = 0.f, s2 = 0.f;
        #pragma unroll
        for (int r = 0; r < 16; r++) { s1 += av[r]; s2 += av[r] * av[r]; }
        s1 += __shfl_xor(s1, 16); s1 += __shfl_xor(s1, 32);
        s2 += __shfl_xor(s2, 16); s2 += __shfl_xor(s2, 32);
        float mu = s1 * (1.f / 64.f);
        float rstd = rsqrtf(s2 * (1.f / 64.f) - mu * mu + 1e-5f);
        float hv[16];
        float sc = 0.f;
        #pragma unroll
        for (int r = 0; r < 16; r++) {
            hv[r] = fmaxf((av[r] - mu) * rstd * lgv[r] + lbv[r], 0.f);
            sc += hv[r] * pnv[r];
        }
        int node = tb + C * 16 + j;
        uint4 o0, o1;
        o0.x = (unsigned)f2h(hv[0])  | ((unsigned)f2h(hv[1])  << 16);
        o0.y = (unsigned)f2h(hv[2])  | ((unsigned)f2h(hv[3])  << 16);
        o0.z = (unsigned)f2h(hv[4])  | ((unsigned)f2h(hv[5])  << 16);
        o0.w = (unsigned)f2h(hv[6])  | ((unsigned)f2h(hv[7])  << 16);
        o1.x = (unsigned)f2h(hv[8])  | ((unsigned)f2h(hv[9])  << 16);
        o1.y = (unsigned)f2h(hv[10]) | ((unsigned)f2h(hv[11]) << 16);
        o1.z = (unsigned)f2h(hv[12]) | ((unsigned)f2h(hv[13]) << 16);
        o1.w = (unsigned)f2h(hv[14]) | ((unsigned)f2h(hv[15]) << 16);
        *(uint4*)(h1h + (size_t)node * 64 + q * 16) = o0;
        *(uint4*)(h1h + (size_t)node * 64 + q * 16 + 8) = o1;
        sc += __shfl_xor(sc, 16); sc += __shfl_xor(sc, 32);
        if (q == 0) scores[node] = sc;
    };
    do_chunk(v0, 0); do_chunk(v1, 1); do_chunk(v2, 2); do_chunk(v3, 3);
}

__global__ __launch_bounds__(64) void post1_kernel(
    const float* __restrict__ agg, const float* __restrict__ cc,
    const float* __restrict__ Wev, const float* __restrict__ gcnb,
    const float* __restrict__ lng, const float* __restrict__ lnb,
    const float* __restrict__ Wp, const float* __restrict__ bp,
    float* __restrict__ out) {
    __shared__ float tile[64 * TPAD];
    const int lane = threadIdx.x;
    const int tb = blockIdx.x * 64;
    const int j = lane & 15, q = lane >> 4;
    float v0[16], v1[16], v2[16], v3[16];
    #pragma unroll
    for (int k = 0; k < 16; k++) { v0[k] = 0.f; v1[k] = 0.f; v2[k] = 0.f; v3[k] = 0.f; }
    for (int db = 0; db < 16; ++db) {
        float wc0 = Wev[(db * 4 + 0) * 64 + lane];
        float wc1 = Wev[(db * 4 + 1) * 64 + lane];
        float wc2 = Wev[(db * 4 + 2) * 64 + lane];
        float wc3 = Wev[(db * 4 + 3) * 64 + lane];
        #pragma unroll
        for (int k = 0; k < 16; k++) {
            float4 a = *(const float4*)(agg + (size_t)(tb + k) * 64 + db * 4);
            v0[k] += a.x * wc0 + a.y * wc1 + a.z * wc2 + a.w * wc3;
        }
        #pragma unroll
        for (int k = 0; k < 16; k++) {
            float4 a = *(const float4*)(agg + (size_t)(tb + 16 + k) * 64 + db * 4);
            v1[k] += a.x * wc0 + a.y * wc1 + a.z * wc2 + a.w * wc3;
        }
        #pragma unroll
        for (int k = 0; k < 16; k++) {
            float4 a = *(const float4*)(agg + (size_t)(tb + 32 + k) * 64 + db * 4);
            v2[k] += a.x * wc0 + a.y * wc1 + a.z * wc2 + a.w * wc3;
        }
        #pragma unroll
        for (int k = 0; k < 16; k++) {
            float4 a = *(const float4*)(agg + (size_t)(tb + 48 + k) * 64 + db * 4);
            v3[k] += a.x * wc0 + a.y * wc1 + a.z * wc2 + a.w * wc3;
        }
    }
    float gL = gcnb[lane];
    float lgv[16], lbv[16];
    #pragma unroll
    for (int r = 0; r < 16; r++) {
        lgv[r] = lng[q * 16 + r];
        lbv[r] = lnb[q * 16 + r];
    }
    float bpv[10];
    #pragma unroll
    for (int t2 = 0; t2 < 10; t2++) bpv[t2] = bp[t2];
    float* trow = tile + lane * TPAD;
    auto do_chunk = [&](float (&VV)[16], int C) {
        __syncthreads();
        #pragma unroll
        for (int k = 0; k < 16; k++) trow[k] = VV[k] + gL * cc[tb + C * 16 + k];
        __syncthreads();
        float av[16];
        #pragma unroll
        for (int r = 0; r < 16; r++) av[r] = tile[(q * 16 + r) * TPAD + j];
        float s1 = 0.f, s2 = 0.f;
        #pragma unroll
        for (int r = 0; r < 16; r++) { s1 += av[r]; s2 += av[r] * av[r]; }
        s1 += __shfl_xor(s1, 16); s1 += __shfl_xor(s1, 32);
        s2 += __shfl_xor(s2, 16); s2 += __shfl_xor(s2, 32);
        float mu = s1 * (1.f / 64.f);
        float rstd = rsqrtf(s2 * (1.f / 64.f) - mu * mu + 1e-5f);
        float hv[16];
        #pragma unroll
        for (int r = 0; r < 16; r++)
            hv[r] = fmaxf((av[r] - mu) * rstd * lgv[r] + lbv[r], 0.f);
        float oa[10];
        #pragma unroll
        for (int t2 = 0; t2 < 10; t2++) oa[t2] = 0.f;
        #pragma unroll
        for (int r = 0; r < 16; r++) {
            const float* wpb = Wp + (size_t)(q * 16 + r) * 2;
            float2 w0 = *(const float2*)(wpb);
            float2 w1 = *(const float2*)(wpb + 128);
            float2 w2 = *(const float2*)(wpb + 256);
            float2 w3 = *(const float2*)(wpb + 384);
            float2 w4 = *(const float2*)(wpb + 512);
            oa[0] += hv[r] * w0.x; oa[1] += hv[r] * w0.y;
            oa[2] += hv[r] * w1.x; oa[3] += hv[r] * w1.y;
            oa[4] += hv[r] * w2.x; oa[5] += hv[r] * w2.y;
            oa[6] += hv[r] * w3.x; oa[7] += hv[r] * w3.y;
            oa[8] += hv[r] * w4.x; oa[9] += hv[r] * w4.y;
        }
        #pragma unroll
        for (int t2 = 0; t2 < 10; t2++) {
            oa[t2] += __shfl_xor(oa[t2], 16);
            oa[t2] += __shfl_xor(oa[t2], 32);
        }
        if (q == 0) {
            int node = tb + C * 16 + j;
            #pragma unroll
            for (int t2 = 0; t2 < 10; t2++) out[(size_t)node * 10 + t2] = oa[t2] + bpv[t2];
        }
    };
    do_chunk(v0, 0); do_chunk(v1, 1); do_chunk(v2, 2); do_chunk(v3, 3);
}

extern "C" void kernel_launch(void* const* d_in, const int* in_sizes, int n_in,
                              void* d_out, int out_size, void* d_ws, size_t ws_size,
                              hipStream_t stream) {
    const float* x     = (const float*)d_in[0];
    const int*   ei    = (const int*)d_in[1];
    const float* ew    = (const float*)d_in[2];
    const float* p0    = (const float*)d_in[5];
    const float* p1    = (const float*)d_in[6];
    const float* Wih0  = (const float*)d_in[7];
    const float* Whh0  = (const float*)d_in[8];
    const float* bih0  = (const float*)d_in[9];
    const float* bhh0  = (const float*)d_in[10];
    const float* Wih1  = (const float*)d_in[11];
    const float* Whh1  = (const float*)d_in[12];
    const float* bih1  = (const float*)d_in[13];
    const float* bhh1  = (const float*)d_in[14];
    const float* gruh0 = (const float*)d_in[15];
    const float* gruh1 = (const float*)d_in[16];
    const float* gcnb0 = (const float*)d_in[17];
    const float* gcnb1 = (const float*)d_in[18];
    const float* lng0  = (const float*)d_in[19];
    const float* lnb0  = (const float*)d_in[20];
    const float* lng1  = (const float*)d_in[21];
    const float* lnb1  = (const float*)d_in[22];
    const float* Wp    = (const float*)d_in[23];
    const float* bp    = (const float*)d_in[24];
    float* out = (float*)d_out;

    // workspace carve
    char* w = (char*)d_ws;
    size_t off = 0;
    auto alloc = [&](size_t bytes) -> void* {
        void* p = w + off;
        off += (bytes + 255) & ~(size_t)255;
        return p;
    };
    int*   rowptr = (int*)alloc((NN + 1) * sizeof(int));
    int2*  evw    = (int2*)alloc((size_t)EE * sizeof(int2));
    float* rsqd   = (float*)alloc(NN * sizeof(float));
    float* invdeg = (float*)alloc(NN * sizeof(float));
    float* scores = (float*)alloc(NN * sizeof(float));
    float* topv   = (float*)alloc(NG * KK * sizeof(float));
    int*   topi   = (int*)alloc(NG * KK * sizeof(int));
    float* Z      = (float*)alloc(16 * 64 * sizeof(float));
    float* ghl    = (float*)alloc((size_t)12288 * 16 * sizeof(float));
    float* Wev    = (float*)alloc(4096 * sizeof(float));
    float* cc     = (float*)alloc(NN * sizeof(float));
    float* agg    = (float*)alloc((size_t)NN * 64 * sizeof(float));
    unsigned short* xh  = (unsigned short*)alloc((size_t)NN * 32 * sizeof(unsigned short));
    unsigned short* h1h = (unsigned short*)alloc((size_t)NN * 64 * sizeof(unsigned short));
    float* pn     = (float*)alloc(96 * sizeof(float));
    int*   bsum   = (int*)alloc(1024 * sizeof(int));
    int*   bsum8  = (int*)alloc(8 * 1024 * sizeof(int));

    // aliases (all dead before their hosts are written):
    // bins64 (16MB) + c2 (8MB) + c2s (8MB) into agg (67MB)
    u64* bins64 = (u64*)agg;
    int* c2  = (int*)((char*)agg + (size_t)8 * NN * sizeof(u64));
    int* c2s = (int*)((char*)c2 + (size_t)8 * NN * sizeof(int));
    // evw_s (EE*8B = 33.5MB) into h1h (NN*64*2B = 33.5MB)
    int2* evw_s = (int2*)h1h;

    // --- CSR build: XCD-exact privatized count + slice-contiguous scatter + compact ---
    hipMemsetAsync(bins64, 0, (size_t)8 * NN * sizeof(u64), stream);
    prep_p<<<1, 64, 0, stream>>>(p0, p1, pn);
    to_f16<<<NN * 32 / 8 / 256, 256, 0, stream>>>(x, xh);
    count64<<<EE / 256, 256, 0, stream>>>(ei, ew, bins64);
    scan1<<<NN / 256, 256, 0, stream>>>(bins64, rowptr, bsum, bsum8, c2, rsqd, invdeg);
    scan2<<<1, 1024, 0, stream>>>(bsum, bsum8);
    scan3<<<NN / 256, 256, 0, stream>>>(rowptr, bsum, bsum8, c2, c2s);
    scatter_edges<<<EE / 256, 256, 0, stream>>>(ei, ew, rsqd, c2, evw_s);
    compact<<<NN / 256, 256, 0, stream>>>(rowptr, c2s, c2, evw_s, evw);

    // --- layer 0 ---
    scores0_kernel<<<NN / 256, 256, 0, stream>>>(x, pn, scores);
    topk_kernel<<<NG, 256, 0, stream>>>(scores, topv, topi);
    z_kernel<<<NG, 32, 0, stream>>>(x, 32, topv, topi, Z);
    hipMemsetAsync(ghl, 0, (size_t)6144 * 16 * sizeof(float), stream);
    gru_matvec<<<dim3(6144 / 16, 4), 256, 0, stream>>>(Whh0, gruh0, ghl, 2048);
    gate_kernel<<<2048 / 256, 256, 0, stream>>>(Wih0, bih0, bhh0, gruh0, ghl, Z, Wev, 2048, 32);
    agg_kernel<32, 5><<<NN / 8, 256, 0, stream>>>(xh, rowptr, evw, rsqd, invdeg, agg, cc);
    post0_kernel<<<NN / 64, 64, 0, stream>>>(agg, cc, Wev, gcnb0, lng0, lnb0, pn + 32, h1h, scores);

    // --- layer 1 ---
    topk_kernel<<<NG, 256, 0, stream>>>(scores, topv, topi);
    z_kernel_h<<<NG, 64, 0, stream>>>(h1h, 64, topv, topi, Z);
    hipMemsetAsync(ghl, 0, (size_t)12288 * 16 * sizeof(float), stream);
    gru_matvec<<<dim3(12288 / 16, 8), 256, 0, stream>>>(Whh1, gruh1, ghl, 4096);
    gate_kernel<<<4096 / 256, 256, 0, stream>>>(Wih1, bih1, bhh1, gruh1, ghl, Z, Wev, 4096, 64);
    agg_kernel<64, 6><<<NN / 4, 256, 0, stream>>>(h1h, rowptr, evw, rsqd, invdeg, agg, cc);
    post1_kernel<<<NN / 64, 64, 0, stream>>>(agg, cc, Wev, gcnb1, lng1, lnb1, Wp, bp, out);
}

// Round 11
// 1421.098 us; speedup vs baseline: 1.3188x; 1.2257x over previous
//
#include <hip/hip_runtime.h>
#include <hip/hip_bf16.h>
#include <hip/hip_fp16.h>

#define NN 262144
#define EE 4194304
#define NG 16
#define NPER 16384
#define KK 7
#define TPAD 20

typedef unsigned long long u64;

__device__ __forceinline__ float wred(float v) {
    #pragma unroll
    for (int o = 32; o > 0; o >>= 1) v += __shfl_xor(v, o);
    return v;
}

__device__ __forceinline__ unsigned short f2h(float f) {
    return __half_as_ushort(__float2half_rn(f));
}
__device__ __forceinline__ float h2f(unsigned short s) {
    return __half2float(__ushort_as_half(s));
}

// real XCD id (exact privatization) [m09]
__device__ __forceinline__ int xcd_id() {
    unsigned x;
    asm volatile("s_getreg_b32 %0, hwreg(HW_REG_XCC_ID)" : "=s"(x));
    return (int)(x & 7);
}

// ---------- p normalization ----------
__global__ void prep_p(const float* __restrict__ p0, const float* __restrict__ p1,
                       float* __restrict__ pn) {
    int t = threadIdx.x;
    float v0 = (t < 32) ? p0[t] : 0.f;
    float s0 = wred(v0 * v0);
    if (t < 32) pn[t] = v0 * rsqrtf(s0);
    float v1 = p1[t];
    float s1 = wred(v1 * v1);
    pn[32 + t] = v1 * rsqrtf(s1);
}

// ---------- CSR build (R7 scheme), XCD-exact privatization ----------
__global__ void count64(const int* __restrict__ ei, const float* __restrict__ ew,
                        u64* __restrict__ bins) {
    int e = blockIdx.x * 256 + threadIdx.x;
    int d = ei[EE + e];
    u64 v = (1ULL << 40) |
        (u64)(unsigned int)__float2uint_rn(ew[e] * 16777216.0f);
    atomicAdd(&bins[(size_t)xcd_id() * NN + d], v);
}

__global__ void scan_block_bins(const u64* __restrict__ bins,
                                int* __restrict__ rowptr, int* __restrict__ bsum,
                                float* __restrict__ rsqd, float* __restrict__ invdeg) {
    __shared__ int sd[256];
    int t = threadIdx.x;
    int i = blockIdx.x * 256 + t;
    u64 s = 0;
    #pragma unroll
    for (int x = 0; x < 8; x++) s += bins[(size_t)x * NN + i];
    int v = (int)(s >> 40);
    float deg = 1.f + (float)(s & ((1ULL << 40) - 1)) * (1.f / 16777216.f);
    rsqd[i] = rsqrtf(deg);
    invdeg[i] = 1.f / deg;
    sd[t] = v;
    __syncthreads();
    #pragma unroll
    for (int off = 1; off < 256; off <<= 1) {
        int add = (t >= off) ? sd[t - off] : 0;
        __syncthreads();
        sd[t] += add;
        __syncthreads();
    }
    rowptr[i] = sd[t] - v;
    if (t == 255) bsum[blockIdx.x] = sd[255];
}

__global__ void scan_partials(int* __restrict__ bsum) {
    __shared__ int sd[1024];
    int t = threadIdx.x;
    int v = bsum[t];
    sd[t] = v;
    __syncthreads();
    #pragma unroll
    for (int off = 1; off < 1024; off <<= 1) {
        int add = (t >= off) ? sd[t - off] : 0;
        __syncthreads();
        sd[t] += add;
        __syncthreads();
    }
    bsum[t] = sd[t] - v;
}

__global__ void scan_add(int* __restrict__ rowptr, const int* __restrict__ bsum) {
    int i = blockIdx.x * 256 + threadIdx.x;
    rowptr[i] += bsum[blockIdx.x];
    if (i == 0) rowptr[NN] = EE;
}

__global__ void cursor_init(const u64* __restrict__ bins,
                            const int* __restrict__ rowptr, int* __restrict__ cursor) {
    int n = blockIdx.x * 256 + threadIdx.x;
    int base = rowptr[n];
    #pragma unroll
    for (int x = 0; x < 8; x++) {
        cursor[(size_t)x * NN + n] = base;
        base += (int)(bins[(size_t)x * NN + n] >> 40);
    }
}

// 4B packed entry: (src << 14) | w_fixed14, w' = ew*rsqd[src] in [0,1)
__global__ void scatter_edges(const int* __restrict__ ei, const float* __restrict__ ew,
                              const float* __restrict__ rsqd, int* __restrict__ cursor,
                              unsigned* __restrict__ evw) {
    int e = blockIdx.x * 256 + threadIdx.x;
    int s = ei[e];
    int d = ei[EE + e];
    float wt = ew[e] * rsqd[s];
    unsigned wq = (unsigned)__float2uint_rn(wt * 16383.f);
    int pos = atomicAdd(&cursor[(size_t)xcd_id() * NN + d], 1);
    evw[pos] = ((unsigned)s << 14) | wq;
}

// ---------- layer-0 scores fused with f32->f16 table conversion ----------
__global__ void scores0_f16(const float* __restrict__ x, const float* __restrict__ pn0,
                            float* __restrict__ scores, unsigned short* __restrict__ xh) {
    __shared__ float p[32];
    if (threadIdx.x < 32) p[threadIdx.x] = pn0[threadIdx.x];
    __syncthreads();
    int n = blockIdx.x * 256 + threadIdx.x;
    const float4* xr = (const float4*)(x + (size_t)n * 32);
    float s = 0.f;
    unsigned wv[16];
    #pragma unroll
    for (int j = 0; j < 8; j++) {
        float4 v = xr[j];
        s += v.x * p[j * 4] + v.y * p[j * 4 + 1] + v.z * p[j * 4 + 2] + v.w * p[j * 4 + 3];
        wv[2 * j]     = (unsigned)f2h(v.x) | ((unsigned)f2h(v.y) << 16);
        wv[2 * j + 1] = (unsigned)f2h(v.z) | ((unsigned)f2h(v.w) << 16);
    }
    uint4* xo = (uint4*)(xh + (size_t)n * 32);
    xo[0] = make_uint4(wv[0], wv[1], wv[2], wv[3]);
    xo[1] = make_uint4(wv[4], wv[5], wv[6], wv[7]);
    xo[2] = make_uint4(wv[8], wv[9], wv[10], wv[11]);
    xo[3] = make_uint4(wv[12], wv[13], wv[14], wv[15]);
    scores[n] = s;
}

// ---------- two-stage per-graph top-7 ----------
// stage 1: 16 chunks of 1024 per graph -> local top-7 candidates (256 blocks total)
__global__ void topk1(const float* __restrict__ scores, float2* __restrict__ cand) {
    int g = blockIdx.x >> 4, c = blockIdx.x & 15;
    int t = threadIdx.x;
    float lv[KK];
    int li[KK];
    #pragma unroll
    for (int j = 0; j < KK; j++) { lv[j] = -INFINITY; li[j] = 0; }
    const float* sg = scores + (size_t)g * NPER + c * 1024;
    #pragma unroll
    for (int it = 0; it < 4; ++it) {
        int idx = it * 256 + t;
        float v = sg[idx];
        if (v > lv[KK - 1]) {
            int j = KK - 1;
            while (j > 0 && lv[j - 1] < v) { lv[j] = lv[j - 1]; li[j] = li[j - 1]; j--; }
            lv[j] = v; li[j] = idx;
        }
    }
    __shared__ float sval[256];
    __shared__ int sidx[256];
    __shared__ int swin;
    int cons = 0;
    for (int r = 0; r < KK; r++) {
        sval[t] = (cons < KK) ? lv[cons] : -INFINITY;
        sidx[t] = t;
        __syncthreads();
        for (int s = 128; s > 0; s >>= 1) {
            if (t < s) {
                if (sval[t + s] > sval[t]) { sval[t] = sval[t + s]; sidx[t] = sidx[t + s]; }
            }
            __syncthreads();
        }
        if (t == 0) swin = sidx[0];
        __syncthreads();
        if (t == swin) {
            cand[blockIdx.x * KK + r] =
                make_float2(lv[cons], __int_as_float(g * NPER + c * 1024 + li[cons]));
            cons++;
        }
        __syncthreads();
    }
}

// stage 2: reduce 16*7=112 candidates per graph -> top-7
__global__ void topk2(const float2* __restrict__ cand, float* __restrict__ topv,
                      int* __restrict__ topi) {
    int g = blockIdx.x, t = threadIdx.x; // 128 threads
    float v = -INFINITY;
    int id = 0;
    if (t < 16 * KK) {
        float2 cv = cand[g * 16 * KK + t];
        v = cv.x;
        id = __float_as_int(cv.y);
    }
    __shared__ float sval[128];
    __shared__ int sidx[128];
    __shared__ int swin;
    for (int r = 0; r < KK; r++) {
        sval[t] = v;
        sidx[t] = t;
        __syncthreads();
        for (int s = 64; s > 0; s >>= 1) {
            if (t < s) {
                if (sval[t + s] > sval[t]) { sval[t] = sval[t + s]; sidx[t] = sidx[t + s]; }
            }
            __syncthreads();
        }
        if (t == 0) swin = sidx[0];
        __syncthreads();
        if (t == swin) {
            topv[g * KK + r] = v;
            topi[g * KK + r] = id;
            v = -INFINITY;
        }
        __syncthreads();
    }
}

// ---------- Z = mean_k tanh(s)*h[idx] ----------
__global__ void z_kernel(const float* __restrict__ h, int din, const float* __restrict__ topv,
                         const int* __restrict__ topi, float* __restrict__ Z) {
    int b = blockIdx.x;
    int d = threadIdx.x;
    if (d >= din) return;
    float acc = 0.f;
    for (int j = 0; j < KK; j++) {
        acc += tanhf(topv[b * KK + j]) * h[(size_t)topi[b * KK + j] * din + d];
    }
    Z[b * din + d] = acc * (1.f / 7.f);
}

__global__ void z_kernel_h(const unsigned short* __restrict__ h, int din,
                           const float* __restrict__ topv, const int* __restrict__ topi,
                           float* __restrict__ Z) {
    int b = blockIdx.x;
    int d = threadIdx.x;
    if (d >= din) return;
    float acc = 0.f;
    for (int j = 0; j < KK; j++) {
        acc += tanhf(topv[b * KK + j]) * h2f(h[(size_t)topi[b * KK + j] * din + d]);
    }
    Z[b * din + d] = acc * (1.f / 7.f);
}

// ---------- GRU: per-slice partial matvec, NO atomics (dealiased by blockIdx.y) ----------
__global__ void gru_matvec(const float* __restrict__ Whh, const float* __restrict__ gh,
                           float* __restrict__ ghl, int P) {
    int t = threadIdx.x;
    int g = t >> 4, l16 = t & 15;
    int row = blockIdx.x * 16 + g;
    int k0 = blockIdx.y * 512;
    float acc[16];
    #pragma unroll
    for (int b = 0; b < 16; b++) acc[b] = 0.f;
    const float* wr = Whh + (size_t)row * P + k0 + l16 * 4;
    const float* gr = gh + k0 + l16 * 4;
    #pragma unroll 2
    for (int kk = 0; kk < 8; ++kk) {
        float4 a = *(const float4*)(wr + kk * 64);
        #pragma unroll
        for (int b = 0; b < 16; b++) {
            float4 gv = *(const float4*)(gr + (size_t)b * P + kk * 64);
            acc[b] += a.x * gv.x + a.y * gv.y + a.z * gv.z + a.w * gv.w;
        }
    }
    size_t sstr = (size_t)gridDim.x * 256; // rows*16
    #pragma unroll
    for (int b = 0; b < 16; b++) {
        float v = acc[b];
        v += __shfl_xor(v, 1); v += __shfl_xor(v, 2);
        v += __shfl_xor(v, 4); v += __shfl_xor(v, 8);
        if (l16 == b) ghl[(size_t)blockIdx.y * sstr + (size_t)row * 16 + b] = v;
    }
}

// ---------- GRU gates + evolved-W mean (sums NS ghl slices) ----------
__global__ void gate_kernel(const float* __restrict__ Wih, const float* __restrict__ bih,
                            const float* __restrict__ bhh, const float* __restrict__ gh,
                            const float* __restrict__ ghl, const float* __restrict__ Zg,
                            float* __restrict__ Wev, int P, int din, int NS) {
    __shared__ float Zs[16 * 64];
    int t = threadIdx.x;
    for (int idx = t; idx < 16 * din; idx += 256) Zs[idx] = Zg[idx];
    __syncthreads();
    int p = blockIdx.x * 256 + t;
    float br = bih[p], bz = bih[P + p], bn = bih[2 * P + p];
    float bhr = bhh[p], bhz = bhh[P + p], bhn = bhh[2 * P + p];
    const float* w_r = Wih + (size_t)p * din;
    const float* w_z = Wih + (size_t)(P + p) * din;
    const float* w_n = Wih + (size_t)(2 * P + p) * din;
    size_t sstr = (size_t)48 * P; // 3P*16
    float wsum = 0.f;
    for (int b = 0; b < 16; b++) {
        float ir = br, iz = bz, inn = bn;
        for (int d = 0; d < din; ++d) {
            float zd = Zs[b * din + d];
            ir += w_r[d] * zd;
            iz += w_z[d] * zd;
            inn += w_n[d] * zd;
        }
        float hr = bhr, hz = bhz, hn = bhn;
        for (int s2 = 0; s2 < NS; s2++) {
            const float* g2 = ghl + (size_t)s2 * sstr;
            hr += g2[(size_t)p * 16 + b];
            hz += g2[(size_t)(P + p) * 16 + b];
            hn += g2[(size_t)(2 * P + p) * 16 + b];
        }
        float r = 1.f / (1.f + expf(-(ir + hr)));
        float z = 1.f / (1.f + expf(-(iz + hz)));
        float n = tanhf(inn + r * hn);
        float hprev = gh[(size_t)b * P + p];
        wsum += (1.f - z) * n + z * hprev;
    }
    Wev[p] = wsum * (1.f / 16.f);
}

// ---------- edge aggregation over f16 rows (R7 structure, 4B packed evw) ----------
template<int DIN, int LSH>
__global__ void agg_kernel(const unsigned short* __restrict__ hin,
                           const int* __restrict__ rowptr, const unsigned* __restrict__ evw,
                           const float* __restrict__ rsqd, const float* __restrict__ invdeg,
                           float* __restrict__ agg, float* __restrict__ cc) {
    int t = threadIdx.x;
    int lane = t & ((1 << LSH) - 1);
    int i = blockIdx.x * (256 >> LSH) + (t >> LSH);
    int e0 = rowptr[i], e1 = rowptr[i + 1];
    float acc = 0.f, csum = 0.f;
    for (int e = e0; e < e1; e += 8) {
        unsigned ev[8];
        #pragma unroll
        for (int j = 0; j < 8; j++) {
            ev[j] = (e + j < e1) ? evw[e + j] : ((unsigned)i << 14);
        }
        float v[8];
        #pragma unroll
        for (int j = 0; j < 8; j++) {
            v[j] = h2f(hin[(size_t)(ev[j] >> 14) * DIN + lane]);
        }
        #pragma unroll
        for (int j = 0; j < 8; j++) {
            float nw = (float)(ev[j] & 16383u) * (1.f / 16383.f);
            csum += nw;
            acc += nw * v[j];
        }
    }
    float rsi = rsqd[i];
    float idg = invdeg[i];
    float r = acc * rsi + h2f(hin[(size_t)i * DIN + lane]) * idg;
    agg[(size_t)i * DIN + lane] = r;
    #pragma unroll
    for (int o = (1 << LSH) >> 1; o > 0; o >>= 1) csum += __shfl_xor(csum, o);
    if (lane == 0) cc[i] = csum * rsi + idg;
}

// ---------- post kernels: 1 wave = 64-node tile, lane = outdim ----------
__global__ __launch_bounds__(64) void post0_kernel(
    const float* __restrict__ agg, const float* __restrict__ cc,
    const float* __restrict__ Wev, const float* __restrict__ gcnb,
    const float* __restrict__ lng, const float* __restrict__ lnb,
    const float* __restrict__ pn1, unsigned short* __restrict__ h1h,
    float* __restrict__ scores) {
    __shared__ float tile[64 * TPAD];
    const int lane = threadIdx.x;
    const int tb = blockIdx.x * 64;
    const int j = lane & 15, q = lane >> 4;
    float v0[16], v1[16], v2[16], v3[16];
    #pragma unroll
    for (int k = 0; k < 16; k++) { v0[k] = 0.f; v1[k] = 0.f; v2[k] = 0.f; v3[k] = 0.f; }
    for (int db = 0; db < 8; ++db) {
        float wc0 = Wev[(db * 4 + 0) * 64 + lane];
        float wc1 = Wev[(db * 4 + 1) * 64 + lane];
        float wc2 = Wev[(db * 4 + 2) * 64 + lane];
        float wc3 = Wev[(db * 4 + 3) * 64 + lane];
        #pragma unroll
        for (int k = 0; k < 16; k++) {
            float4 a = *(const float4*)(agg + (size_t)(tb + k) * 32 + db * 4);
            v0[k] += a.x * wc0 + a.y * wc1 + a.z * wc2 + a.w * wc3;
        }
        #pragma unroll
        for (int k = 0; k < 16; k++) {
            float4 a = *(const float4*)(agg + (size_t)(tb + 16 + k) * 32 + db * 4);
            v1[k] += a.x * wc0 + a.y * wc1 + a.z * wc2 + a.w * wc3;
        }
        #pragma unroll
        for (int k = 0; k < 16; k++) {
            float4 a = *(const float4*)(agg + (size_t)(tb + 32 + k) * 32 + db * 4);
            v2[k] += a.x * wc0 + a.y * wc1 + a.z * wc2 + a.w * wc3;
        }
        #pragma unroll
        for (int k = 0; k < 16; k++) {
            float4 a = *(const float4*)(agg + (size_t)(tb + 48 + k) * 32 + db * 4);
            v3[k] += a.x * wc0 + a.y * wc1 + a.z * wc2 + a.w * wc3;
        }
    }
    float gL = gcnb[lane];
    float lgv[16], lbv[16], pnv[16];
    #pragma unroll
    for (int r = 0; r < 16; r++) {
        lgv[r] = lng[q * 16 + r];
        lbv[r] = lnb[q * 16 + r];
        pnv[r] = pn1[q * 16 + r];
    }
    float* trow = tile + lane * TPAD;
    auto do_chunk = [&](float (&VV)[16], int C) {
        __syncthreads();
        #pragma unroll
        for (int k = 0; k < 16; k++) trow[k] = VV[k] + gL * cc[tb + C * 16 + k];
        __syncthreads();
        float av[16];
        #pragma unroll
        for (int r = 0; r < 16; r++) av[r] = tile[(q * 16 + r) * TPAD + j];
        float s1 = 0.f, s2 = 0.f;
        #pragma unroll
        for (int r = 0; r < 16; r++) { s1 += av[r]; s2 += av[r] * av[r]; }
        s1 += __shfl_xor(s1, 16); s1 += __shfl_xor(s1, 32);
        s2 += __shfl_xor(s2, 16); s2 += __shfl_xor(s2, 32);
        float mu = s1 * (1.f / 64.f);
        float rstd = rsqrtf(s2 * (1.f / 64.f) - mu * mu + 1e-5f);
        float hv[16];
        float sc = 0.f;
        #pragma unroll
        for (int r = 0; r < 16; r++) {
            hv[r] = fmaxf((av[r] - mu) * rstd * lgv[r] + lbv[r], 0.f);
            sc += hv[r] * pnv[r];
        }
        int node = tb + C * 16 + j;
        uint4 o0, o1;
        o0.x = (unsigned)f2h(hv[0])  | ((unsigned)f2h(hv[1])  << 16);
        o0.y = (unsigned)f2h(hv[2])  | ((unsigned)f2h(hv[3])  << 16);
        o0.z = (unsigned)f2h(hv[4])  | ((unsigned)f2h(hv[5])  << 16);
        o0.w = (unsigned)f2h(hv[6])  | ((unsigned)f2h(hv[7])  << 16);
        o1.x = (unsigned)f2h(hv[8])  | ((unsigned)f2h(hv[9])  << 16);
        o1.y = (unsigned)f2h(hv[10]) | ((unsigned)f2h(hv[11]) << 16);
        o1.z = (unsigned)f2h(hv[12]) | ((unsigned)f2h(hv[13]) << 16);
        o1.w = (unsigned)f2h(hv[14]) | ((unsigned)f2h(hv[15]) << 16);
        *(uint4*)(h1h + (size_t)node * 64 + q * 16) = o0;
        *(uint4*)(h1h + (size_t)node * 64 + q * 16 + 8) = o1;
        sc += __shfl_xor(sc, 16); sc += __shfl_xor(sc, 32);
        if (q == 0) scores[node] = sc;
    };
    do_chunk(v0, 0); do_chunk(v1, 1); do_chunk(v2, 2); do_chunk(v3, 3);
}

__global__ __launch_bounds__(64) void post1_kernel(
    const float* __restrict__ agg, const float* __restrict__ cc,
    const float* __restrict__ Wev, const float* __restrict__ gcnb,
    const float* __restrict__ lng, const float* __restrict__ lnb,
    const float* __restrict__ Wp, const float* __restrict__ bp,
    float* __restrict__ out) {
    __shared__ float tile[64 * TPAD];
    const int lane = threadIdx.x;
    const int tb = blockIdx.x * 64;
    const int j = lane & 15, q = lane >> 4;
    float v0[16], v1[16], v2[16], v3[16];
    #pragma unroll
    for (int k = 0; k < 16; k++) { v0[k] = 0.f; v1[k] = 0.f; v2[k] = 0.f; v3[k] = 0.f; }
    for (int db = 0; db < 16; ++db) {
        float wc0 = Wev[(db * 4 + 0) * 64 + lane];
        float wc1 = Wev[(db * 4 + 1) * 64 + lane];
        float wc2 = Wev[(db * 4 + 2) * 64 + lane];
        float wc3 = Wev[(db * 4 + 3) * 64 + lane];
        #pragma unroll
        for (int k = 0; k < 16; k++) {
            float4 a = *(const float4*)(agg + (size_t)(tb + k) * 64 + db * 4);
            v0[k] += a.x * wc0 + a.y * wc1 + a.z * wc2 + a.w * wc3;
        }
        #pragma unroll
        for (int k = 0; k < 16; k++) {
            float4 a = *(const float4*)(agg + (size_t)(tb + 16 + k) * 64 + db * 4);
            v1[k] += a.x * wc0 + a.y * wc1 + a.z * wc2 + a.w * wc3;
        }
        #pragma unroll
        for (int k = 0; k < 16; k++) {
            float4 a = *(const float4*)(agg + (size_t)(tb + 32 + k) * 64 + db * 4);
            v2[k] += a.x * wc0 + a.y * wc1 + a.z * wc2 + a.w * wc3;
        }
        #pragma unroll
        for (int k = 0; k < 16; k++) {
            float4 a = *(const float4*)(agg + (size_t)(tb + 48 + k) * 64 + db * 4);
            v3[k] += a.x * wc0 + a.y * wc1 + a.z * wc2 + a.w * wc3;
        }
    }
    float gL = gcnb[lane];
    float lgv[16], lbv[16];
    #pragma unroll
    for (int r = 0; r < 16; r++) {
        lgv[r] = lng[q * 16 + r];
        lbv[r] = lnb[q * 16 + r];
    }
    float bpv[10];
    #pragma unroll
    for (int t2 = 0; t2 < 10; t2++) bpv[t2] = bp[t2];
    float* trow = tile + lane * TPAD;
    auto do_chunk = [&](float (&VV)[16], int C) {
        __syncthreads();
        #pragma unroll
        for (int k = 0; k < 16; k++) trow[k] = VV[k] + gL * cc[tb + C * 16 + k];
        __syncthreads();
        float av[16];
        #pragma unroll
        for (int r = 0; r < 16; r++) av[r] = tile[(q * 16 + r) * TPAD + j];
        float s1 = 0.f, s2 = 0.f;
        #pragma unroll
        for (int r = 0; r < 16; r++) { s1 += av[r]; s2 += av[r] * av[r]; }
        s1 += __shfl_xor(s1, 16); s1 += __shfl_xor(s1, 32);
        s2 += __shfl_xor(s2, 16); s2 += __shfl_xor(s2, 32);
        float mu = s1 * (1.f / 64.f);
        float rstd = rsqrtf(s2 * (1.f / 64.f) - mu * mu + 1e-5f);
        float hv[16];
        #pragma unroll
        for (int r = 0; r < 16; r++)
            hv[r] = fmaxf((av[r] - mu) * rstd * lgv[r] + lbv[r], 0.f);
        float oa[10];
        #pragma unroll
        for (int t2 = 0; t2 < 10; t2++) oa[t2] = 0.f;
        #pragma unroll
        for (int r = 0; r < 16; r++) {
            const float* wpb = Wp + (size_t)(q * 16 + r) * 2;
            float2 w0 = *(const float2*)(wpb);
            float2 w1 = *(const float2*)(wpb + 128);
            float2 w2 = *(const float2*)(wpb + 256);
            float2 w3 = *(const float2*)(wpb + 384);
            float2 w4 = *(const float2*)(wpb + 512);
            oa[0] += hv[r] * w0.x; oa[1] += hv[r] * w0.y;
            oa[2] += hv[r] * w1.x; oa[3] += hv[r] * w1.y;
            oa[4] += hv[r] * w2.x; oa[5] += hv[r] * w2.y;
            oa[6] += hv[r] * w3.x; oa[7] += hv[r] * w3.y;
            oa[8] += hv[r] * w4.x; oa[9] += hv[r] * w4.y;
        }
        #pragma unroll
        for (int t2 = 0; t2 < 10; t2++) {
            oa[t2] += __shfl_xor(oa[t2], 16);
            oa[t2] += __shfl_xor(oa[t2], 32);
        }
        if (q == 0) {
            int node = tb + C * 16 + j;
            #pragma unroll
            for (int t2 = 0; t2 < 10; t2++) out[(size_t)node * 10 + t2] = oa[t2] + bpv[t2];
        }
    };
    do_chunk(v0, 0); do_chunk(v1, 1); do_chunk(v2, 2); do_chunk(v3, 3);
}

extern "C" void kernel_launch(void* const* d_in, const int* in_sizes, int n_in,
                              void* d_out, int out_size, void* d_ws, size_t ws_size,
                              hipStream_t stream) {
    const float* x     = (const float*)d_in[0];
    const int*   ei    = (const int*)d_in[1];
    const float* ew    = (const float*)d_in[2];
    const float* p0    = (const float*)d_in[5];
    const float* p1    = (const float*)d_in[6];
    const float* Wih0  = (const float*)d_in[7];
    const float* Whh0  = (const float*)d_in[8];
    const float* bih0  = (const float*)d_in[9];
    const float* bhh0  = (const float*)d_in[10];
    const float* Wih1  = (const float*)d_in[11];
    const float* Whh1  = (const float*)d_in[12];
    const float* bih1  = (const float*)d_in[13];
    const float* bhh1  = (const float*)d_in[14];
    const float* gruh0 = (const float*)d_in[15];
    const float* gruh1 = (const float*)d_in[16];
    const float* gcnb0 = (const float*)d_in[17];
    const float* gcnb1 = (const float*)d_in[18];
    const float* lng0  = (const float*)d_in[19];
    const float* lnb0  = (const float*)d_in[20];
    const float* lng1  = (const float*)d_in[21];
    const float* lnb1  = (const float*)d_in[22];
    const float* Wp    = (const float*)d_in[23];
    const float* bp    = (const float*)d_in[24];
    float* out = (float*)d_out;

    // workspace carve
    char* w = (char*)d_ws;
    size_t off = 0;
    auto alloc = [&](size_t bytes) -> void* {
        void* p = w + off;
        off += (bytes + 255) & ~(size_t)255;
        return p;
    };
    int*      rowptr = (int*)alloc((NN + 1) * sizeof(int));
    unsigned* evw    = (unsigned*)alloc((size_t)EE * sizeof(unsigned));
    float*    rsqd   = (float*)alloc(NN * sizeof(float));
    float*    invdeg = (float*)alloc(NN * sizeof(float));
    float*    scores = (float*)alloc(NN * sizeof(float));
    float*    topv   = (float*)alloc(NG * KK * sizeof(float));
    int*      topi   = (int*)alloc(NG * KK * sizeof(int));
    float2*   cand   = (float2*)alloc(NG * 16 * KK * sizeof(float2));
    float*    Z      = (float*)alloc(16 * 64 * sizeof(float));
    float*    ghl    = (float*)alloc((size_t)8 * 196608 * sizeof(float));
    float*    Wev    = (float*)alloc(4096 * sizeof(float));
    float*    cc     = (float*)alloc(NN * sizeof(float));
    float*    agg    = (float*)alloc((size_t)NN * 64 * sizeof(float));
    unsigned short* xh  = (unsigned short*)alloc((size_t)NN * 32 * sizeof(unsigned short));
    unsigned short* h1h = (unsigned short*)alloc((size_t)NN * 64 * sizeof(unsigned short));
    float*    pn     = (float*)alloc(96 * sizeof(float));
    int*      bsum   = (int*)alloc(1024 * sizeof(int));

    // bins64 (16MB) + cursor (8MB) alias into agg (67MB, dead before agg written)
    u64* bins64 = (u64*)agg;
    int* cursor = (int*)((char*)agg + (size_t)8 * NN * sizeof(u64));

    // --- CSR build (shared by both layers) ---
    hipMemsetAsync(bins64, 0, (size_t)8 * NN * sizeof(u64), stream);
    prep_p<<<1, 64, 0, stream>>>(p0, p1, pn);
    count64<<<EE / 256, 256, 0, stream>>>(ei, ew, bins64);
    scan_block_bins<<<NN / 256, 256, 0, stream>>>(bins64, rowptr, bsum, rsqd, invdeg);
    scan_partials<<<1, 1024, 0, stream>>>(bsum);
    scan_add<<<NN / 256, 256, 0, stream>>>(rowptr, bsum);
    cursor_init<<<NN / 256, 256, 0, stream>>>(bins64, rowptr, cursor);
    scatter_edges<<<EE / 256, 256, 0, stream>>>(ei, ew, rsqd, cursor, evw);

    // --- layer 0 ---
    scores0_f16<<<NN / 256, 256, 0, stream>>>(x, pn, scores, xh);
    topk1<<<NG * 16, 256, 0, stream>>>(scores, cand);
    topk2<<<NG, 128, 0, stream>>>(cand, topv, topi);
    z_kernel<<<NG, 32, 0, stream>>>(x, 32, topv, topi, Z);
    gru_matvec<<<dim3(6144 / 16, 4), 256, 0, stream>>>(Whh0, gruh0, ghl, 2048);
    gate_kernel<<<2048 / 256, 256, 0, stream>>>(Wih0, bih0, bhh0, gruh0, ghl, Z, Wev, 2048, 32, 4);
    agg_kernel<32, 5><<<NN / 8, 256, 0, stream>>>(xh, rowptr, evw, rsqd, invdeg, agg, cc);
    post0_kernel<<<NN / 64, 64, 0, stream>>>(agg, cc, Wev, gcnb0, lng0, lnb0, pn + 32, h1h, scores);

    // --- layer 1 ---
    topk1<<<NG * 16, 256, 0, stream>>>(scores, cand);
    topk2<<<NG, 128, 0, stream>>>(cand, topv, topi);
    z_kernel_h<<<NG, 64, 0, stream>>>(h1h, 64, topv, topi, Z);
    gru_matvec<<<dim3(12288 / 16, 8), 256, 0, stream>>>(Whh1, gruh1, ghl, 4096);
    gate_kernel<<<4096 / 256, 256, 0, stream>>>(Wih1, bih1, bhh1, gruh1, ghl, Z, Wev, 4096, 64, 8);
    agg_kernel<64, 6><<<NN / 4, 256, 0, stream>>>(h1h, rowptr, evw, rsqd, invdeg, agg, cc);
    post1_kernel<<<NN / 64, 64, 0, stream>>>(agg, cc, Wev, gcnb1, lng1, lnb1, Wp, bp, out);
}